// Round 1
// 1072.212 us; speedup vs baseline: 1.0432x; 1.0432x over previous
//
#include <hip/hip_runtime.h>
#include <hip/hip_bf16.h>
#include <math.h>

#define N_NODES 40000
#define N_EDGES 320000
#define T_ITERS 3

typedef __attribute__((ext_vector_type(8))) short short8;
typedef __attribute__((ext_vector_type(4))) short short4v;
typedef __attribute__((ext_vector_type(4))) float f32x4;

static __device__ __forceinline__ short f2bf(float f) {
    union { float f; unsigned u; } x; x.f = f;
    unsigned r = (x.u + 0x7fffu + ((x.u >> 16) & 1u)) >> 16;
    return (short)r;
}
static __device__ __forceinline__ float bf2f(short s) {
    union { unsigned u; float f; } x; x.u = ((unsigned)(unsigned short)s) << 16;
    return x.f;
}

// ---------------------------------------------------------------------------
// MFMA GEMM (bf16 A): C[M,NC] = A[M,K] @ W[NC,K]^T + bias. Tile 64 x 32*NI.
// Used for QKV: NI=4, grid (625, 3).
// ---------------------------------------------------------------------------
template<int NI>
__global__ __launch_bounds__(256) void gemm_bf16(
    const short* __restrict__ A, const short* __restrict__ W,
    const float* __restrict__ bias, short* __restrict__ Cb,
    int M, int K, int NC)
{
    constexpr int NT = 32 * NI;
    __shared__ __align__(16) short As[64 * 40];
    __shared__ __align__(16) short Ws[NT * 40];

    const int tid  = threadIdx.x;
    const int lane = tid & 63, wid = tid >> 6;
    const int wm = wid & 1, wn = wid >> 1;
    const int t16 = lane & 15, quad = lane >> 4;
    const long blockM = (long)blockIdx.x * 64;
    const int colBase = blockIdx.y * NT;

    f32x4 acc[2][NI];
    for (int i = 0; i < 2; i++)
        for (int j = 0; j < NI; j++)
            acc[i][j] = (f32x4){0.f, 0.f, 0.f, 0.f};

    for (int k0 = 0; k0 < K; k0 += 32) {
        {
            const int r = tid >> 2, c = (tid & 3) * 8;
            *(short8*)&As[r * 40 + c] = *(const short8*)(A + (blockM + r) * K + k0 + c);
        }
        for (int gg = 0; gg < NI / 2; gg++) {
            const int chunk = tid + gg * 256;
            const int r = chunk >> 2, c = (chunk & 3) * 8;
            *(short8*)&Ws[r * 40 + c] =
                *(const short8*)(W + (long)(colBase + r) * K + k0 + c);
        }
        __syncthreads();
        short8 a0 = *(const short8*)&As[(wm * 32 + t16) * 40 + quad * 8];
        short8 a1 = *(const short8*)&As[(wm * 32 + 16 + t16) * 40 + quad * 8];
        for (int ni = 0; ni < NI; ni++) {
            short8 bf = *(const short8*)&Ws[(wn * 16 * NI + ni * 16 + t16) * 40 + quad * 8];
            acc[0][ni] = __builtin_amdgcn_mfma_f32_16x16x32_bf16(a0, bf, acc[0][ni], 0, 0, 0);
            acc[1][ni] = __builtin_amdgcn_mfma_f32_16x16x32_bf16(a1, bf, acc[1][ni], 0, 0, 0);
        }
        __syncthreads();
    }

    for (int mi = 0; mi < 2; mi++)
        for (int ni = 0; ni < NI; ni++) {
            const int gc = colBase + wn * 16 * NI + ni * 16 + t16;
            for (int r = 0; r < 4; r++) {
                long gr = blockM + wm * 32 + mi * 16 + quad * 4 + r;
                float v = acc[mi][ni][r];
                if (bias) v += bias[gc];
                Cb[gr * (long)NC + gc] = f2bf(v);
            }
        }
}

// ---------------------------------------------------------------------------
// EKV GEMM: EKV[slot] = ea[e] @ [wk;wv]^T + [bk;bv]  (bf16 [E,256]).
// Output is written in CSR SLOT order (eslot permutation) so edge_attn
// streams it sequentially 3x. Restructure vs prior version:
//   - whole 64x128 A tile staged ONCE (8 back-to-back float4 HBM loads per
//     thread -> bf16 -> As[64][136]); only L2-resident W staged per K-chunk.
//   - one HBM-drain barrier instead of four; launch_bounds(256,4) + 37.9 KB
//     LDS -> 4 blocks/CU.
// ---------------------------------------------------------------------------
__global__ __launch_bounds__(256, 4) void ekv_kernel(
    const float* __restrict__ ea, const short* __restrict__ Wkv,
    const float* __restrict__ bkv, const int* __restrict__ eslot,
    short* __restrict__ EKV)
{
    __shared__ __align__(16) char smem[64 * 136 * 2 + 256 * 40 * 2]; // 37.9 KB
    short* As = (short*)smem;                    // [64][136] bf16 A tile
    short* Ws = (short*)(smem + 64 * 136 * 2);   // [256][40] W chunk
    short* Cs = (short*)smem;                    // [64][276] out transpose (union)

    const int tid  = threadIdx.x;
    const int lane = tid & 63, wid = tid >> 6;
    const int t16 = lane & 15, quad = lane >> 4;
    const long blockM = (long)blockIdx.x * 64;

    // Stage full A tile: 64 rows x 128 f32 -> bf16. 4 threads per row.
    {
        const int r = tid >> 2, c0 = (tid & 3) * 32;
        const float* gp = ea + (blockM + r) * 128 + c0;
        for (int half = 0; half < 2; half++) {
            float4 v0 = *(const float4*)(gp + half * 16);
            float4 v1 = *(const float4*)(gp + half * 16 + 4);
            float4 v2 = *(const float4*)(gp + half * 16 + 8);
            float4 v3 = *(const float4*)(gp + half * 16 + 12);
            short8 s0, s1;
            s0[0] = f2bf(v0.x); s0[1] = f2bf(v0.y); s0[2] = f2bf(v0.z); s0[3] = f2bf(v0.w);
            s0[4] = f2bf(v1.x); s0[5] = f2bf(v1.y); s0[6] = f2bf(v1.z); s0[7] = f2bf(v1.w);
            s1[0] = f2bf(v2.x); s1[1] = f2bf(v2.y); s1[2] = f2bf(v2.z); s1[3] = f2bf(v2.w);
            s1[4] = f2bf(v3.x); s1[5] = f2bf(v3.y); s1[6] = f2bf(v3.z); s1[7] = f2bf(v3.w);
            *(short8*)&As[r * 136 + c0 + half * 16]     = s0;
            *(short8*)&As[r * 136 + c0 + half * 16 + 8] = s1;
        }
    }

    f32x4 acc[4][4];
    for (int i = 0; i < 4; i++)
        for (int j = 0; j < 4; j++)
            acc[i][j] = (f32x4){0.f, 0.f, 0.f, 0.f};

    for (int k0 = 0; k0 < 128; k0 += 32) {
        for (int g = 0; g < 4; g++) {
            const int idx = tid + g * 256;
            const int r = idx >> 2, c = (idx & 3) * 8;
            *(short8*)&Ws[r * 40 + c] = *(const short8*)(Wkv + (long)r * 128 + k0 + c);
        }
        __syncthreads();  // k0==0: also covers As staging
        short8 a[4];
        for (int mi = 0; mi < 4; mi++)
            a[mi] = *(const short8*)&As[(mi * 16 + t16) * 136 + k0 + quad * 8];
        for (int ni = 0; ni < 4; ni++) {
            short8 bf = *(const short8*)&Ws[(wid * 64 + ni * 16 + t16) * 40 + quad * 8];
            for (int mi = 0; mi < 4; mi++)
                acc[mi][ni] = __builtin_amdgcn_mfma_f32_16x16x32_bf16(a[mi], bf, acc[mi][ni], 0, 0, 0);
        }
        __syncthreads();  // guard Ws overwrite next iter / Cs overwrite after
    }

    for (int mi = 0; mi < 4; mi++)
        for (int ni = 0; ni < 4; ni++) {
            const int col = wid * 64 + ni * 16 + t16;
            const float bv_ = bkv[col];
            for (int r = 0; r < 4; r++) {
                const int row = mi * 16 + quad * 4 + r;
                Cs[row * 276 + col] = f2bf(acc[mi][ni][r] + bv_);
            }
        }
    __syncthreads();
    // Permuted write: row (edge blockM+row) lands at its CSR slot.
    for (int it = 0; it < 8; it++) {
        const int idx = it * 256 + tid;
        const int row = idx >> 5, c8 = idx & 31;
        const long orow = eslot[blockM + row];
        *(short8*)(EKV + orow * 256 + c8 * 8) = *(const short8*)&Cs[row * 276 + c8 * 8];
    }
}

// ---------------------------------------------------------------------------
// Edge attention. One wave per node, 8 edges in flight (8 lanes/edge,
// 16 dims/lane). EKV is in CSR slot order -> sequential streaming reads.
// ---------------------------------------------------------------------------
__global__ __launch_bounds__(256) void edge_attn_kernel(
    const short* __restrict__ QKVb, const short* __restrict__ EKV,
    const int* __restrict__ rowptr, const int* __restrict__ esrc,
    short* __restrict__ outb)
{
    const int wid = threadIdx.x >> 6, lane = threadIdx.x & 63;
    const int n = blockIdx.x * 4 + wid;
    if (n >= N_NODES) return;
    const int g = lane >> 3, l8 = lane & 7;
    const int d0 = l8 * 16;
    const float scale = 0.17677669529663687f;  // 1/sqrt(32)

    short8 q0 = *(const short8*)&QKVb[(long)n * 384 + d0];
    short8 q1 = *(const short8*)&QKVb[(long)n * 384 + d0 + 8];
    float qf[16];
#pragma unroll
    for (int j = 0; j < 8; j++) { qf[j] = bf2f(q0[j]); qf[8 + j] = bf2f(q1[j]); }

    const int beg = rowptr[n], end = rowptr[n + 1];
    float acc[16];
#pragma unroll
    for (int j = 0; j < 16; j++) acc[j] = 0.f;
    float ssum = 0.f;

    for (int i0 = beg; i0 < end; i0 += 8) {
        const int i = i0 + g;
        const bool valid = i < end;
        const long ii = valid ? i : beg;
        const long s = esrc[ii];
        short8 k0 = *(const short8*)&EKV[ii * 256 + d0];
        short8 k1 = *(const short8*)&EKV[ii * 256 + d0 + 8];
        short8 xk0 = *(const short8*)&QKVb[s * 384 + 128 + d0];
        short8 xk1 = *(const short8*)&QKVb[s * 384 + 128 + d0 + 8];
        short8 v0 = *(const short8*)&EKV[ii * 256 + 128 + d0];
        short8 v1 = *(const short8*)&EKV[ii * 256 + 128 + d0 + 8];
        short8 xv0 = *(const short8*)&QKVb[s * 384 + 256 + d0];
        short8 xv1 = *(const short8*)&QKVb[s * 384 + 256 + d0 + 8];
        float dot = 0.f;
#pragma unroll
        for (int j = 0; j < 8; j++) {
            dot += qf[j] * (bf2f(k0[j]) + bf2f(xk0[j]));
            dot += qf[8 + j] * (bf2f(k1[j]) + bf2f(xk1[j]));
        }
        dot += __shfl_xor(dot, 1);   // head's other 16 dims
        float a = valid ? __expf(dot * scale) : 0.f;
        ssum += a;
#pragma unroll
        for (int j = 0; j < 8; j++) {
            acc[j]     += a * (bf2f(v0[j]) + bf2f(xv0[j]));
            acc[8 + j] += a * (bf2f(v1[j]) + bf2f(xv1[j]));
        }
    }
    // reduce over the 8 edge-groups (lane bits 3,4,5)
#pragma unroll
    for (int o = 8; o < 64; o <<= 1) {
#pragma unroll
        for (int j = 0; j < 16; j++) acc[j] += __shfl_xor(acc[j], o);
        ssum += __shfl_xor(ssum, o);
    }
    if (g == 0) {
        float inv = 1.0f / (ssum + 1e-16f);
        short8 o0, o1;
#pragma unroll
        for (int j = 0; j < 8; j++) { o0[j] = f2bf(acc[j] * inv); o1[j] = f2bf(acc[8 + j] * inv); }
        *(short8*)&outb[(long)n * 128 + d0] = o0;
        *(short8*)&outb[(long)n * 128 + d0 + 8] = o1;
    }
}

// ---------------------------------------------------------------------------
// Fused Wao+LN1+FFN: att = LN1(attraw@Wao^T + b_ao + x);
// m = LN2( gelu(att@Wint^T+b_int) @ Wout^T + b_out + att ).
// Block: 64 rows, 4 waves (wave = 16 rows x 128 cols).
// ---------------------------------------------------------------------------
__global__ __launch_bounds__(256) void ffn_kernel(
    const short* __restrict__ attraw, const short* __restrict__ x,
    const short* __restrict__ Wao, const short* __restrict__ Wint,
    const short* __restrict__ Wout, const float* __restrict__ b_ao,
    const float* __restrict__ b_int, const float* __restrict__ b_out,
    const float* __restrict__ ln1_g, const float* __restrict__ ln1_b,
    const float* __restrict__ ln2_g, const float* __restrict__ ln2_b,
    short* __restrict__ Mout)
{
    __shared__ __align__(16) short As[64 * 136];   // x -> att
    __shared__ __align__(16) short Is[64 * 136];   // attraw -> inter chunks
    __shared__ __align__(16) short Ws[128 * 40];

    const int tid  = threadIdx.x;
    const int lane = tid & 63, wid = tid >> 6;
    const int t16 = lane & 15, quad = lane >> 4;
    const long blockM = (long)blockIdx.x * 64;

    // stage x -> As, attraw -> Is
    {
        const int r = tid >> 2, c = (tid & 3) * 32;
        const long gr = blockM + r;
        for (int j = 0; j < 4; j++) {
            *(short8*)&As[r * 136 + c + j * 8] = *(const short8*)(x + gr * 128 + c + j * 8);
            *(short8*)&Is[r * 136 + c + j * 8] = *(const short8*)(attraw + gr * 128 + c + j * 8);
        }
    }
    __syncthreads();

    // phase 0: attraw @ Wao^T
    f32x4 acc0[8];
    for (int j = 0; j < 8; j++) acc0[j] = (f32x4){0.f, 0.f, 0.f, 0.f};
    for (int k0 = 0; k0 < 128; k0 += 32) {
        const int r = tid >> 1, c = (tid & 1) * 16;
        *(short8*)&Ws[r * 40 + c]     = *(const short8*)(Wao + (long)r * 128 + k0 + c);
        *(short8*)&Ws[r * 40 + c + 8] = *(const short8*)(Wao + (long)r * 128 + k0 + c + 8);
        __syncthreads();
        short8 a = *(const short8*)&Is[(wid * 16 + t16) * 136 + k0 + quad * 8];
        for (int ni = 0; ni < 8; ni++) {
            short8 bf = *(const short8*)&Ws[(ni * 16 + t16) * 40 + quad * 8];
            acc0[ni] = __builtin_amdgcn_mfma_f32_16x16x32_bf16(a, bf, acc0[ni], 0, 0, 0);
        }
        __syncthreads();
    }
    // epilogue 0: +b_ao +x, LN1, att -> As (1:1 thread ownership, no hazard)
    for (int r = 0; r < 4; r++) {
        const int row = wid * 16 + quad * 4 + r;
        float vals[8];
        float s = 0.f;
        for (int ni = 0; ni < 8; ni++) {
            const int col = ni * 16 + t16;
            float v = acc0[ni][r] + b_ao[col] + bf2f(As[row * 136 + col]);
            vals[ni] = v;
            s += v;
        }
        for (int o = 1; o < 16; o <<= 1) s += __shfl_xor(s, o);
        float u = s * (1.0f / 128.0f);
        float vs = 0.f;
        for (int ni = 0; ni < 8; ni++) { float d = vals[ni] - u; vals[ni] = d; vs += d * d; }
        for (int o = 1; o < 16; o <<= 1) vs += __shfl_xor(vs, o);
        float rstd = rsqrtf(vs * (1.0f / 128.0f) + 1e-12f);
        for (int ni = 0; ni < 8; ni++) {
            const int col = ni * 16 + t16;
            As[row * 136 + col] = f2bf(ln1_g[col] * vals[ni] * rstd + ln1_b[col]);
        }
    }
    __syncthreads();

    // FFN
    f32x4 acc2[8];
    for (int j = 0; j < 8; j++) acc2[j] = (f32x4){0.f, 0.f, 0.f, 0.f};
    for (int kc = 0; kc < 4; kc++) {
        f32x4 acc1[8];
        for (int j = 0; j < 8; j++) acc1[j] = (f32x4){0.f, 0.f, 0.f, 0.f};
        for (int k0 = 0; k0 < 128; k0 += 32) {
            const int r = tid >> 1, c = (tid & 1) * 16;
            *(short8*)&Ws[r * 40 + c] =
                *(const short8*)(Wint + (long)(kc * 128 + r) * 128 + k0 + c);
            *(short8*)&Ws[r * 40 + c + 8] =
                *(const short8*)(Wint + (long)(kc * 128 + r) * 128 + k0 + c + 8);
            __syncthreads();
            short8 a = *(const short8*)&As[(wid * 16 + t16) * 136 + k0 + quad * 8];
            for (int ni = 0; ni < 8; ni++) {
                short8 bf = *(const short8*)&Ws[(ni * 16 + t16) * 40 + quad * 8];
                acc1[ni] = __builtin_amdgcn_mfma_f32_16x16x32_bf16(a, bf, acc1[ni], 0, 0, 0);
            }
            __syncthreads();
        }
        for (int ni = 0; ni < 8; ni++) {
            const int col = ni * 16 + t16;
            const float bi = b_int[kc * 128 + col];
            for (int r = 0; r < 4; r++) {
                const int row = wid * 16 + quad * 4 + r;
                float v = acc1[ni][r] + bi;
                v = 0.5f * v * (1.0f + erff(v * 0.70710678118654752f));
                Is[row * 136 + col] = f2bf(v);
            }
        }
        __syncthreads();
        for (int k0 = 0; k0 < 128; k0 += 32) {
            const int r = tid >> 1, c = (tid & 1) * 16;
            *(short8*)&Ws[r * 40 + c] =
                *(const short8*)(Wout + (long)r * 512 + kc * 128 + k0 + c);
            *(short8*)&Ws[r * 40 + c + 8] =
                *(const short8*)(Wout + (long)r * 512 + kc * 128 + k0 + c + 8);
            __syncthreads();
            short8 a = *(const short8*)&Is[(wid * 16 + t16) * 136 + k0 + quad * 8];
            for (int ni = 0; ni < 8; ni++) {
                short8 bf = *(const short8*)&Ws[(ni * 16 + t16) * 40 + quad * 8];
                acc2[ni] = __builtin_amdgcn_mfma_f32_16x16x32_bf16(a, bf, acc2[ni], 0, 0, 0);
            }
            __syncthreads();
        }
    }

    // epilogue 2: +b_out + att, LN2, store
    for (int r = 0; r < 4; r++) {
        const int row = wid * 16 + quad * 4 + r;
        const long gr = blockM + row;
        float vals[8];
        float s = 0.f;
        for (int ni = 0; ni < 8; ni++) {
            const int col = ni * 16 + t16;
            float v = acc2[ni][r] + b_out[col] + bf2f(As[row * 136 + col]);
            vals[ni] = v;
            s += v;
        }
        for (int o = 1; o < 16; o <<= 1) s += __shfl_xor(s, o);
        float u = s * (1.0f / 128.0f);
        float vs = 0.f;
        for (int ni = 0; ni < 8; ni++) { float d = vals[ni] - u; vals[ni] = d; vs += d * d; }
        for (int o = 1; o < 16; o <<= 1) vs += __shfl_xor(vs, o);
        float rstd = rsqrtf(vs * (1.0f / 128.0f) + 1e-12f);
        for (int ni = 0; ni < 8; ni++) {
            const int col = ni * 16 + t16;
            Mout[gr * 128 + col] = f2bf(ln2_g[col] * vals[ni] * rstd + ln2_b[col]);
        }
    }
}

// ---------------------------------------------------------------------------
// Fused GRU: [m|h](N,256) @ Wg(512,256)^T -> {ir+hr, iz+hz, in, hn}
// + gates + h' + LN3.  Block 64 rows; wave w -> cols w*128.
// ---------------------------------------------------------------------------
template<bool FINAL>
__global__ __launch_bounds__(256) void gru_kernel(
    const short* __restrict__ m, const short* __restrict__ h,
    const short* __restrict__ Wg, const float* __restrict__ bg,
    const float* __restrict__ g3, const float* __restrict__ b3,
    short* __restrict__ hout, void* __restrict__ xout)
{
    __shared__ __align__(16) char smem[64 * 520 * 2];
    short* As = (short*)smem;
    short* Ws = (short*)(smem + 64 * 40 * 2);
    short* Os = (short*)smem;

    const int tid  = threadIdx.x;
    const int lane = tid & 63, wid = tid >> 6;
    const int t16 = lane & 15, quad = lane >> 4;
    const long blockM = (long)blockIdx.x * 64;

    f32x4 acc[4][8];
    for (int i = 0; i < 4; i++)
        for (int j = 0; j < 8; j++)
            acc[i][j] = (f32x4){0.f, 0.f, 0.f, 0.f};

    for (int k0 = 0; k0 < 256; k0 += 32) {
        const short* src = (k0 < 128) ? m : h;
        {
            const int r = tid >> 2, c = (tid & 3) * 8;
            *(short8*)&As[r * 40 + c] =
                *(const short8*)(src + (blockM + r) * 128 + (k0 & 127) + c);
        }
        for (int g = 0; g < 8; g++) {
            const int idx = tid + g * 256;
            const int r = idx >> 2, c = (idx & 3) * 8;
            *(short8*)&Ws[r * 40 + c] = *(const short8*)(Wg + (long)r * 256 + k0 + c);
        }
        __syncthreads();
        short8 a[4];
        for (int mi = 0; mi < 4; mi++)
            a[mi] = *(const short8*)&As[(mi * 16 + t16) * 40 + quad * 8];
        for (int ni = 0; ni < 8; ni++) {
            short8 bf = *(const short8*)&Ws[(wid * 128 + ni * 16 + t16) * 40 + quad * 8];
            for (int mi = 0; mi < 4; mi++)
                acc[mi][ni] = __builtin_amdgcn_mfma_f32_16x16x32_bf16(a[mi], bf, acc[mi][ni], 0, 0, 0);
        }
        __syncthreads();
    }

    for (int mi = 0; mi < 4; mi++)
        for (int ni = 0; ni < 8; ni++) {
            const int col = wid * 128 + ni * 16 + t16;
            const float bb = bg[col];
            for (int r = 0; r < 4; r++) {
                const int row = mi * 16 + quad * 4 + r;
                Os[row * 520 + col] = f2bf(acc[mi][ni][r] + bb);
            }
        }
    __syncthreads();

    {
        const int row = tid >> 2;
        const int c0 = (tid & 3) * 32;
        const long gr = blockM + row;
        float hv[32];
        for (int j = 0; j < 4; j++) {
            short8 hpv = *(const short8*)(h + gr * 128 + c0 + j * 8);
            short8 orv = *(const short8*)&Os[row * 520 + c0 + j * 8];
            short8 ozv = *(const short8*)&Os[row * 520 + 128 + c0 + j * 8];
            short8 onv = *(const short8*)&Os[row * 520 + 256 + c0 + j * 8];
            short8 ohv = *(const short8*)&Os[row * 520 + 384 + c0 + j * 8];
            for (int q = 0; q < 8; q++) {
                float rr = 1.f / (1.f + __expf(-bf2f(orv[q])));
                float zz = 1.f / (1.f + __expf(-bf2f(ozv[q])));
                float nn = tanhf(bf2f(onv[q]) + rr * bf2f(ohv[q]));
                float hpq = bf2f(hpv[q]);
                hv[j * 8 + q] = (1.f - zz) * nn + zz * hpq;
            }
        }
        float s = 0.f;
        for (int j = 0; j < 32; j++) s += hv[j];
        s += __shfl_xor(s, 1); s += __shfl_xor(s, 2);
        float u = s * (1.0f / 128.0f);
        float vs = 0.f;
        for (int j = 0; j < 32; j++) { float d = hv[j] - u; vs += d * d; }
        vs += __shfl_xor(vs, 1); vs += __shfl_xor(vs, 2);
        float rstd = rsqrtf(vs * (1.0f / 128.0f) + 1e-12f);
        for (int j = 0; j < 4; j++) {
            short8 o;
            for (int q = 0; q < 8; q++) o[q] = f2bf(hv[j * 8 + q]);
            *(short8*)(hout + gr * 128 + c0 + j * 8) = o;
        }
        if (FINAL) {
            float* xo = (float*)xout;
            for (int j = 0; j < 8; j++) {
                float4 o;
                o.x = g3[c0 + j * 4 + 0] * (hv[j * 4 + 0] - u) * rstd + b3[c0 + j * 4 + 0];
                o.y = g3[c0 + j * 4 + 1] * (hv[j * 4 + 1] - u) * rstd + b3[c0 + j * 4 + 1];
                o.z = g3[c0 + j * 4 + 2] * (hv[j * 4 + 2] - u) * rstd + b3[c0 + j * 4 + 2];
                o.w = g3[c0 + j * 4 + 3] * (hv[j * 4 + 3] - u) * rstd + b3[c0 + j * 4 + 3];
                *(float4*)&xo[gr * 128 + c0 + j * 4] = o;
            }
        } else {
            short* xo = (short*)xout;
            for (int j = 0; j < 4; j++) {
                short8 o;
                for (int q = 0; q < 8; q++) {
                    const int c = c0 + j * 8 + q;
                    o[q] = f2bf(g3[c] * (hv[j * 8 + q] - u) * rstd + b3[c]);
                }
                *(short8*)(xo + gr * 128 + c0 + j * 8) = o;
            }
        }
    }
}

// ---------------------------------------------------------------------------
// CSR build
// ---------------------------------------------------------------------------
__global__ void count_kernel(const int* __restrict__ dst, int* __restrict__ cnt) {
    int e = blockIdx.x * 256 + threadIdx.x;
    if (e < N_EDGES) atomicAdd(&cnt[dst[e]], 1);
}

__global__ __launch_bounds__(1024) void scan_kernel(const int* __restrict__ cnt,
                                                    int* __restrict__ rowptr) {
    __shared__ int lds[1024];
    const int tid = threadIdx.x;
    const int CH = 40;
    const int base = tid * CH;
    int sum = 0;
    for (int j = 0; j < CH; j++) { int i = base + j; if (i < N_NODES) sum += cnt[i]; }
    lds[tid] = sum;
    __syncthreads();
    for (int off = 1; off < 1024; off <<= 1) {
        int v = (tid >= off) ? lds[tid - off] : 0;
        __syncthreads();
        lds[tid] += v;
        __syncthreads();
    }
    int run = lds[tid] - sum;
    for (int j = 0; j < CH; j++) {
        int i = base + j;
        if (i < N_NODES) { rowptr[i] = run; run += cnt[i]; }
    }
    if (tid == 1023) rowptr[N_NODES] = lds[1023];
}

__global__ void fill_kernel(const int* __restrict__ src, const int* __restrict__ dst,
                            const int* __restrict__ rowptr, int* __restrict__ wo,
                            int* __restrict__ esrc, int* __restrict__ eslot) {
    int e = blockIdx.x * 256 + threadIdx.x;
    if (e < N_EDGES) {
        int d = dst[e];
        int pos = atomicAdd(&wo[d], 1);
        int slot = rowptr[d] + pos;
        esrc[slot] = src[e];
        eslot[e] = slot;
    }
}

// ---------------------------------------------------------------------------
// Helpers
// ---------------------------------------------------------------------------
__global__ void cvt_kernel(const float* __restrict__ s, short* __restrict__ d, int n) {
    int i = (blockIdx.x * 256 + threadIdx.x) * 4;
    if (i < n) {
        float4 v = *(const float4*)(s + i);
        short4v sv;
        sv.x = f2bf(v.x); sv.y = f2bf(v.y); sv.z = f2bf(v.z); sv.w = f2bf(v.w);
        *(short4v*)(d + i) = sv;
    }
}
__global__ void bias_cat_kernel(const float* __restrict__ bq, const float* __restrict__ bk,
                                const float* __restrict__ bv, float* __restrict__ bqkv,
                                float* __restrict__ bkv) {
    int i = blockIdx.x * 256 + threadIdx.x;
    if (i < 384) bqkv[i] = (i < 128) ? bq[i] : 0.0f;
    if (i < 256) bkv[i] = (i < 128) ? bk[i] : bv[i - 128];
}
__global__ void build_wg_kernel(const float* __restrict__ wih, const float* __restrict__ whh,
                                const float* __restrict__ bih, const float* __restrict__ bhh,
                                short* __restrict__ Wg, float* __restrict__ bg) {
    int idx = blockIdx.x * 256 + threadIdx.x;
    if (idx < 512 * 256) {
        int r = idx >> 8, k = idx & 255;
        float v;
        if (r < 256)      v = (k < 128) ? wih[r * 128 + k] : whh[r * 128 + k - 128];
        else if (r < 384) v = (k < 128) ? wih[r * 128 + k] : 0.f;
        else              v = (k < 128) ? 0.f : whh[(r - 128) * 128 + k - 128];
        Wg[idx] = f2bf(v);
    }
    if (idx < 512) {
        float b;
        if (idx < 256)      b = bih[idx] + bhh[idx];
        else if (idx < 384) b = bih[idx];
        else                b = bhh[idx - 128];
        bg[idx] = b;
    }
}

// ---------------------------------------------------------------------------
extern "C" void kernel_launch(void* const* d_in, const int* in_sizes, int n_in,
                              void* d_out, int out_size, void* d_ws, size_t ws_size,
                              hipStream_t stream) {
    const float* x_in  = (const float*)d_in[0];
    const int*   eidx  = (const int*)d_in[1];
    const float* ea    = (const float*)d_in[2];
    const float* wq    = (const float*)d_in[3];
    const float* bq    = (const float*)d_in[4];
    const float* wk    = (const float*)d_in[5];
    const float* bk    = (const float*)d_in[6];
    const float* wv    = (const float*)d_in[7];
    const float* bv    = (const float*)d_in[8];
    const float* w_ao  = (const float*)d_in[9];
    const float* b_ao  = (const float*)d_in[10];
    const float* ln1_g = (const float*)d_in[11];
    const float* ln1_b = (const float*)d_in[12];
    const float* w_int = (const float*)d_in[13];
    const float* b_int = (const float*)d_in[14];
    const float* w_out = (const float*)d_in[15];
    const float* b_out = (const float*)d_in[16];
    const float* ln2_g = (const float*)d_in[17];
    const float* ln2_b = (const float*)d_in[18];
    const float* w_ih  = (const float*)d_in[19];
    const float* w_hh  = (const float*)d_in[20];
    const float* b_ih  = (const float*)d_in[21];
    const float* b_hh  = (const float*)d_in[22];
    const float* ln3_g = (const float*)d_in[23];
    const float* ln3_b = (const float*)d_in[24];
    const int* srcv = eidx;
    const int* dstv = eidx + N_EDGES;

    char* ws = (char*)d_ws;
    size_t off = 0;
    auto alloc = [&](size_t bytes) -> void* {
        void* p = ws + off;
        off += (bytes + 255) & ~(size_t)255;
        return p;
    };
    short* EKV  = (short*)alloc((size_t)N_EDGES * 256 * 2);
    short* Wcat = (short*)alloc(384 * 128 * 2);
    short* Wao  = (short*)alloc(128 * 128 * 2);
    short* Wint = (short*)alloc(512 * 128 * 2);
    short* Wout = (short*)alloc(128 * 512 * 2);
    short* Wg   = (short*)alloc(512 * 256 * 2);
    float* bqkv = (float*)alloc(384 * 4);
    float* bkv  = (float*)alloc(256 * 4);
    float* bg   = (float*)alloc(512 * 4);
    int* cnt    = (int*)alloc((size_t)N_NODES * 4);
    int* wo     = (int*)alloc((size_t)N_NODES * 4);
    int* rowptr = (int*)alloc((size_t)(N_NODES + 1) * 4);
    int* esrc   = (int*)alloc((size_t)N_EDGES * 4);
    int* eslot  = (int*)alloc((size_t)N_EDGES * 4);
    short* xb     = (short*)alloc((size_t)N_NODES * 128 * 2);
    short* QKVb   = (short*)alloc((size_t)N_NODES * 384 * 2);
    short* attraw = (short*)alloc((size_t)N_NODES * 128 * 2);
    short* mbuf   = (short*)alloc((size_t)N_NODES * 128 * 2);
    short* hbuf   = (short*)alloc((size_t)N_NODES * 128 * 2);
    short* xbuf   = (short*)alloc((size_t)N_NODES * 128 * 2);
    if (off > ws_size) return;

    cvt_kernel<<<16, 256, 0, stream>>>(wq, Wcat, 16384);
    cvt_kernel<<<16, 256, 0, stream>>>(wk, Wcat + 16384, 16384);
    cvt_kernel<<<16, 256, 0, stream>>>(wv, Wcat + 32768, 16384);
    cvt_kernel<<<16, 256, 0, stream>>>(w_ao, Wao, 16384);
    cvt_kernel<<<64, 256, 0, stream>>>(w_int, Wint, 65536);
    cvt_kernel<<<64, 256, 0, stream>>>(w_out, Wout, 65536);
    cvt_kernel<<<5000, 256, 0, stream>>>(x_in, xb, N_NODES * 128);
    bias_cat_kernel<<<2, 256, 0, stream>>>(bq, bk, bv, bqkv, bkv);
    build_wg_kernel<<<512, 256, 0, stream>>>(w_ih, w_hh, b_ih, b_hh, Wg, bg);

    hipMemsetAsync(cnt, 0, (size_t)N_NODES * 4, stream);
    hipMemsetAsync(wo, 0, (size_t)N_NODES * 4, stream);
    count_kernel<<<1250, 256, 0, stream>>>(dstv, cnt);
    scan_kernel<<<1, 1024, 0, stream>>>(cnt, rowptr);
    fill_kernel<<<1250, 256, 0, stream>>>(srcv, dstv, rowptr, wo, esrc, eslot);

    ekv_kernel<<<5000, 256, 0, stream>>>(ea, Wcat + 128 * 128, bkv, eslot, EKV);

    const short* xcur = xb;
    const short* hcur = xb;
    for (int t = 0; t < T_ITERS; t++) {
        gemm_bf16<4><<<dim3(625, 3), 256, 0, stream>>>(
            xcur, Wcat, bqkv, QKVb, N_NODES, 128, 384);
        edge_attn_kernel<<<10000, 256, 0, stream>>>(QKVb, EKV, rowptr, esrc, attraw);
        ffn_kernel<<<625, 256, 0, stream>>>(
            attraw, xcur, Wao, Wint, Wout, b_ao, b_int, b_out,
            ln1_g, ln1_b, ln2_g, ln2_b, mbuf);
        if (t == T_ITERS - 1)
            gru_kernel<true><<<625, 256, 0, stream>>>(
                mbuf, hcur, Wg, bg, ln3_g, ln3_b, hbuf, d_out);
        else
            gru_kernel<false><<<625, 256, 0, stream>>>(
                mbuf, hcur, Wg, bg, ln3_g, ln3_b, hbuf, xbuf);
        xcur = xbuf;
        hcur = hbuf;
    }
}